// Round 1
// baseline (151.884 us; speedup 1.0000x reference)
//
#include <hip/hip_runtime.h>

// MultiHeadAttention_3753801417043 — MI355X/gfx950
// B=32, S=512, D_IN=128, N_HEAD=8, DIM_MODEL=512, SCALE=8.
// Pipeline (all NT GEMMs, split-bf16 3-pass for fp32-grade accuracy):
//   W_eff[k][n] = sum_h W[h*128+k][n]  (concat([x]*8)@W == x@W_eff)
//   Q/K/V = x @ W_eff + b              [16384 x 512]
//   scores[b] = Q[b]·K[b]^T / 8        [512 x 512] per batch
//   attn = softmax rows
//   out[b] = V[b]·attn[b]^T            (einsum 'bik,bjk->bij')

typedef unsigned short u16;
typedef __attribute__((ext_vector_type(8))) short bf16x8;   // 8 bf16 in 4 VGPRs
typedef __attribute__((ext_vector_type(4))) float f32x4;

#define BM 128
#define BN 128
#define BK 64

__device__ inline u16 f2bf(float f) {            // round-to-nearest-even fp32->bf16
  unsigned u = __float_as_uint(f);
  u = u + 0x7fffu + ((u >> 16) & 1u);
  return (u16)(u >> 16);
}
__device__ inline float bf2f(u16 h) { return __uint_as_float(((unsigned)h) << 16); }

// async global->LDS, 16B per lane (wave-uniform LDS base + lane*16; our layout is linear)
__device__ inline void gl16(const u16* g, u16* l) {
  __builtin_amdgcn_global_load_lds(
      (const __attribute__((address_space(1))) unsigned int*)g,
      (__attribute__((address_space(3))) unsigned int*)l, 16, 0, 0);
}

// ---- W_eff prep: WT[t][n][k] = sum_h W_t[h*128+k][n], split into bf16 hi/lo ----
__global__ __launch_bounds__(256)
void prep_w(const float* __restrict__ Wq, const float* __restrict__ Wk,
            const float* __restrict__ Wv,
            u16* __restrict__ WTh, u16* __restrict__ WTl) {
  int idx = blockIdx.x * 256 + threadIdx.x;        // [t][n][k], k fastest
  if (idx >= 3 * 512 * 128) return;
  int t = idx >> 16;
  int r = idx & 65535;
  int n = r >> 7;
  int k = r & 127;
  const float* W = (t == 0) ? Wq : (t == 1) ? Wk : Wv;
  float s = 0.f;
#pragma unroll
  for (int h = 0; h < 8; ++h) s += W[(h * 128 + k) * 512 + n];
  u16 hi = f2bf(s);
  WTh[idx] = hi;
  WTl[idx] = f2bf(s - bf2f(hi));
}

// ---- x split into bf16 hi/lo ----
__global__ __launch_bounds__(256)
void split_x(const float* __restrict__ x, u16* __restrict__ xh, u16* __restrict__ xl, int n) {
  int i = blockIdx.x * 256 + threadIdx.x;
  if (i >= n) return;
  float v = x[i];
  u16 h = f2bf(v);
  xh[i] = h;
  xl[i] = f2bf(v - bf2f(h));
}

// ---- NT GEMM, 3-pass split bf16: C = (Ah+Al)(Bh+Bl)^T ≈ AhBh + AhBl + AlBh ----
// EPI 0: C fp32 * scale.  EPI 1: C + bias -> bf16 hi/lo pair.
// LDS: linear dest for global_load_lds; source col pre-swizzled (col8 ^= row&7),
// reads apply the same XOR -> conflict-free ds_read_b128 (rule #21 both-sides).
template <int EPI>
__global__ __launch_bounds__(256, 2)
void nt_gemm3(const u16* __restrict__ Ah, const u16* __restrict__ Al,
              const u16* __restrict__ Bh, const u16* __restrict__ Bl,
              float* __restrict__ Cf, u16* __restrict__ Ch, u16* __restrict__ Cl,
              const float* __restrict__ bias,
              int K, int lda, int ldb, int ldc,
              int mtiles, int ntiles,
              long batchA, long batchB, long batchC, float scale) {
  __shared__ __align__(16) u16 lds[4][BM * BK];   // Ah, Al, Bh, Bl tiles (4 x 16KB)

  int tid = threadIdx.x;
  int bid = blockIdx.x;
  int tpb = mtiles * ntiles;
  int b  = bid / tpb;
  int t  = bid - b * tpb;
  int mt = t / ntiles;
  int nt = t - mt * ntiles;

  const u16* pAh = Ah + (long)b * batchA + (long)mt * BM * lda;
  const u16* pAl = Al + (long)b * batchA + (long)mt * BM * lda;
  const u16* pBh = Bh + (long)b * batchB + (long)nt * BN * ldb;
  const u16* pBl = Bl + (long)b * batchB + (long)nt * BN * ldb;

  int lane = tid & 63;
  int wv   = tid >> 6;
  int wm   = (wv >> 1) << 6;       // wave 2x2 grid, 64x64 per wave
  int wn   = (wv & 1) << 6;
  int frow = lane & 15;            // mfma A/B row within 16
  int fk   = (lane >> 4) << 3;     // k-subgroup base (8 contiguous bf16)

  f32x4 acc[4][4];
#pragma unroll
  for (int i = 0; i < 4; ++i)
#pragma unroll
    for (int j = 0; j < 4; ++j) {
      f32x4 z = {0.f, 0.f, 0.f, 0.f};
      acc[i][j] = z;
    }

  int kt = K >> 6;
  for (int kk = 0; kk < kt; ++kk) {
    int k0 = kk << 6;
    // stage 4 tiles: 1024 16B-chunks per tile, 4 per thread
#pragma unroll
    for (int j = 0; j < 4; ++j) {
      int c = j * 256 + tid;
      int row = c >> 3;
      int scol = (((c & 7) ^ (row & 7)) << 3);   // inverse-swizzled source column
      long ga = (long)row * lda + k0 + scol;
      long gb = (long)row * ldb + k0 + scol;
      int lo = c << 3;
      gl16(pAh + ga, &lds[0][lo]);
      gl16(pAl + ga, &lds[1][lo]);
      gl16(pBh + gb, &lds[2][lo]);
      gl16(pBl + gb, &lds[3][lo]);
    }
    __syncthreads();   // compiler drains vmcnt before s_barrier

#pragma unroll
    for (int ks = 0; ks < 2; ++ks) {
      int kb = (ks << 5) + fk;
      bf16x8 a_h[4], a_l[4], b_h[4], b_l[4];
#pragma unroll
      for (int i = 0; i < 4; ++i) {
        int ar = wm + (i << 4) + frow;
        int ao = ar * BK + (kb ^ ((ar & 7) << 3));   // swizzled read
        a_h[i] = *(const bf16x8*)&lds[0][ao];
        a_l[i] = *(const bf16x8*)&lds[1][ao];
        int br = wn + (i << 4) + frow;
        int bo = br * BK + (kb ^ ((br & 7) << 3));
        b_h[i] = *(const bf16x8*)&lds[2][bo];
        b_l[i] = *(const bf16x8*)&lds[3][bo];
      }
#pragma unroll
      for (int i = 0; i < 4; ++i)
#pragma unroll
        for (int j = 0; j < 4; ++j) {
          acc[i][j] = __builtin_amdgcn_mfma_f32_16x16x32_bf16(a_h[i], b_h[j], acc[i][j], 0, 0, 0);
          acc[i][j] = __builtin_amdgcn_mfma_f32_16x16x32_bf16(a_h[i], b_l[j], acc[i][j], 0, 0, 0);
          acc[i][j] = __builtin_amdgcn_mfma_f32_16x16x32_bf16(a_l[i], b_h[j], acc[i][j], 0, 0, 0);
        }
    }
    __syncthreads();
  }

  // C/D layout (m89-verified): col = lane&15, row = (lane>>4)*4 + reg
  int rbase = mt * BM + wm + ((lane >> 4) << 2);
  int cbase = nt * BN + wn + (lane & 15);
  if (EPI == 0) {
    float* C = Cf + (long)b * batchC;
#pragma unroll
    for (int i = 0; i < 4; ++i)
#pragma unroll
      for (int j = 0; j < 4; ++j)
#pragma unroll
        for (int r = 0; r < 4; ++r)
          C[(long)(rbase + (i << 4) + r) * ldc + cbase + (j << 4)] = acc[i][j][r] * scale;
  } else {
#pragma unroll
    for (int i = 0; i < 4; ++i)
#pragma unroll
      for (int j = 0; j < 4; ++j)
#pragma unroll
        for (int r = 0; r < 4; ++r) {
          int col = cbase + (j << 4);
          float v = acc[i][j][r] + bias[col];
          long o = (long)(rbase + (i << 4) + r) * ldc + col;
          u16 h = f2bf(v);
          Ch[o] = h;
          Cl[o] = f2bf(v - bf2f(h));
        }
  }
}

// ---- softmax over rows of 512, one wave per row; writes bf16 hi/lo ----
__global__ __launch_bounds__(256)
void softmax_rows(const float* __restrict__ S, u16* __restrict__ Ah, u16* __restrict__ Al) {
  int row  = (blockIdx.x << 2) + (threadIdx.x >> 6);
  int lane = threadIdx.x & 63;
  const float* s = S + (long)row * 512;
  float v[8];
  float m = -3.4e38f;
#pragma unroll
  for (int j = 0; j < 8; ++j) { v[j] = s[(j << 6) + lane]; m = fmaxf(m, v[j]); }
#pragma unroll
  for (int o = 32; o > 0; o >>= 1) m = fmaxf(m, __shfl_xor(m, o));
  float sum = 0.f;
#pragma unroll
  for (int j = 0; j < 8; ++j) { v[j] = __expf(v[j] - m); sum += v[j]; }
#pragma unroll
  for (int o = 32; o > 0; o >>= 1) sum += __shfl_xor(sum, o);
  float inv = 1.f / sum;
  long base = (long)row * 512;
#pragma unroll
  for (int j = 0; j < 8; ++j) {
    float a = v[j] * inv;
    u16 h = f2bf(a);
    Ah[base + (j << 6) + lane] = h;
    Al[base + (j << 6) + lane] = f2bf(a - bf2f(h));
  }
}

extern "C" void kernel_launch(void* const* d_in, const int* in_sizes, int n_in,
                              void* d_out, int out_size, void* d_ws, size_t ws_size,
                              hipStream_t stream) {
  const float* x  = (const float*)d_in[0];
  const float* Wq = (const float*)d_in[1];
  const float* bq = (const float*)d_in[2];
  const float* Wk = (const float*)d_in[3];
  const float* bk = (const float*)d_in[4];
  const float* Wv = (const float*)d_in[5];
  const float* bv = (const float*)d_in[6];
  float* out = (float*)d_out;

  char* ws = (char*)d_ws;
  size_t off = 0;
  auto alloc = [&](size_t bytes) -> char* {
    char* p = ws + off;
    off = (off + bytes + 255) & ~(size_t)255;
    return p;
  };
  u16* WTh = (u16*)alloc((size_t)3 * 512 * 128 * 2);
  u16* WTl = (u16*)alloc((size_t)3 * 512 * 128 * 2);
  u16* xh  = (u16*)alloc((size_t)16384 * 128 * 2);
  u16* xl  = (u16*)alloc((size_t)16384 * 128 * 2);
  u16* Qh  = (u16*)alloc((size_t)16384 * 512 * 2);
  u16* Ql  = (u16*)alloc((size_t)16384 * 512 * 2);
  u16* Kh  = (u16*)alloc((size_t)16384 * 512 * 2);
  u16* Kl  = (u16*)alloc((size_t)16384 * 512 * 2);
  u16* Vh  = (u16*)alloc((size_t)16384 * 512 * 2);
  u16* Vl  = (u16*)alloc((size_t)16384 * 512 * 2);
  float* sc = (float*)alloc((size_t)32 * 512 * 512 * 4);
  u16* ah = Qh;   // attn reuses Q buffers (dead after scores GEMM)
  u16* al = Ql;

  prep_w<<<768, 256, 0, stream>>>(Wq, Wk, Wv, WTh, WTl);
  split_x<<<8192, 256, 0, stream>>>(x, xh, xl, 16384 * 128);

  // projections: M=16384, N=512, K=128 -> 128x4 tiles = 512 blocks each
  nt_gemm3<1><<<512, 256, 0, stream>>>(xh, xl, WTh,          WTl,          nullptr, Qh, Ql, bq,
                                       128, 128, 128, 512, 128, 4, 0, 0, 0, 1.f);
  nt_gemm3<1><<<512, 256, 0, stream>>>(xh, xl, WTh + 65536,  WTl + 65536,  nullptr, Kh, Kl, bk,
                                       128, 128, 128, 512, 128, 4, 0, 0, 0, 1.f);
  nt_gemm3<1><<<512, 256, 0, stream>>>(xh, xl, WTh + 131072, WTl + 131072, nullptr, Vh, Vl, bv,
                                       128, 128, 128, 512, 128, 4, 0, 0, 0, 1.f);

  // scores[b] = Q K^T / 8 : batch=32, 4x4 tiles -> 512 blocks
  nt_gemm3<0><<<512, 256, 0, stream>>>(Qh, Ql, Kh, Kl, sc, nullptr, nullptr, nullptr,
                                       512, 512, 512, 512, 4, 4,
                                       262144, 262144, 262144, 0.125f);

  softmax_rows<<<4096, 256, 0, stream>>>(sc, ah, al);

  // out[b] = V attn^T : fp32 to d_out
  nt_gemm3<0><<<512, 256, 0, stream>>>(Vh, Vl, ah, al, out, nullptr, nullptr, nullptr,
                                       512, 512, 512, 512, 4, 4,
                                       262144, 262144, 262144, 1.f);
}

// Round 2
// 105.346 us; speedup vs baseline: 1.4418x; 1.4418x over previous
//
#include <hip/hip_runtime.h>

// MultiHeadAttention_3753801417043 — MI355X/gfx950
// B=32, S=512, D_IN=128, N_HEAD=8, DIM_MODEL=512, SCALE=8.
// Pipeline (all NT GEMMs, mixed split-bf16 precision tuned to the 1.5e-2 budget):
//   W_eff[k][n] = sum_h W[h*128+k][n]  (concat([x]*8)@W == x@W_eff)
//   Q/K/V = x @ W_eff + b     3-pass split-bf16; Q keeps hi+lo, K/V hi only
//   scores[b] = Q·K^T / 8     2-pass: (Qh+Ql)·Kh^T
//   attn = softmax rows       bf16 hi only
//   out[b] = V·attn^T         1-pass: Vh·Ah^T

typedef unsigned short u16;
typedef __attribute__((ext_vector_type(8))) short bf16x8;   // 8 bf16 in 4 VGPRs
typedef __attribute__((ext_vector_type(4))) float f32x4;

#define BM 128
#define BN 128
#define BK 64

__device__ inline u16 f2bf(float f) {            // round-to-nearest-even fp32->bf16
  unsigned u = __float_as_uint(f);
  u = u + 0x7fffu + ((u >> 16) & 1u);
  return (u16)(u >> 16);
}
__device__ inline float bf2f(u16 h) { return __uint_as_float(((unsigned)h) << 16); }

// async global->LDS, 16B per lane (wave-uniform LDS base + lane*16; linear layout)
__device__ inline void gl16(const u16* g, u16* l) {
  __builtin_amdgcn_global_load_lds(
      (const __attribute__((address_space(1))) unsigned int*)g,
      (__attribute__((address_space(3))) unsigned int*)l, 16, 0, 0);
}

// ---- W_eff prep: WT[t][n][k] = sum_h W_t[h*128+k][n], split into bf16 hi/lo ----
__global__ __launch_bounds__(256)
void prep_w(const float* __restrict__ Wq, const float* __restrict__ Wk,
            const float* __restrict__ Wv,
            u16* __restrict__ WTh, u16* __restrict__ WTl) {
  int idx = blockIdx.x * 256 + threadIdx.x;        // [t][n][k], k fastest
  if (idx >= 3 * 512 * 128) return;
  int t = idx >> 16;
  int r = idx & 65535;
  int n = r >> 7;
  int k = r & 127;
  const float* W = (t == 0) ? Wq : (t == 1) ? Wk : Wv;
  float s = 0.f;
#pragma unroll
  for (int h = 0; h < 8; ++h) s += W[(h * 128 + k) * 512 + n];
  u16 hi = f2bf(s);
  WTh[idx] = hi;
  WTl[idx] = f2bf(s - bf2f(hi));
}

// ---- x split into bf16 hi/lo ----
__global__ __launch_bounds__(256)
void split_x(const float* __restrict__ x, u16* __restrict__ xh, u16* __restrict__ xl, int n) {
  int i = blockIdx.x * 256 + threadIdx.x;
  if (i >= n) return;
  float v = x[i];
  u16 h = f2bf(v);
  xh[i] = h;
  xl[i] = f2bf(v - bf2f(h));
}

// ---- NT GEMM, templated pass structure ----
// MODE 0: 1-pass  Ah·Bh            -> fp32 C * scale          (2 LDS tiles, 32 KB)
// MODE 1: 2-pass  (Ah+Al)·Bh       -> fp32 C * scale          (3 LDS tiles, 48 KB)
// MODE 2: 3-pass  AhBh+AhBl+AlBh   -> +bias, bf16 hi+lo out   (4 LDS tiles, 64 KB)
// MODE 3: 3-pass  AhBh+AhBl+AlBh   -> +bias, bf16 hi out      (4 LDS tiles, 64 KB)
// LDS: linear dest for global_load_lds; source col pre-swizzled (col8 ^= row&7),
// reads apply the same XOR -> conflict-free ds_read_b128 (rule #21 both-sides).
template <int MODE>
__global__ __launch_bounds__(256, 2)
void nt_gemm(const u16* __restrict__ Ah, const u16* __restrict__ Al,
             const u16* __restrict__ Bh, const u16* __restrict__ Bl,
             float* __restrict__ Cf, u16* __restrict__ Ch, u16* __restrict__ Cl,
             const float* __restrict__ bias,
             int K, int lda, int ldb, int ldc,
             int mtiles, int ntiles,
             long batchA, long batchB, long batchC, float scale) {
  constexpr int NST = (MODE == 0) ? 2 : (MODE == 1) ? 3 : 4;
  constexpr int IB  = (MODE == 0) ? 1 : 2;        // lds index of Bh
  __shared__ __align__(16) u16 lds[NST][BM * BK];

  int tid = threadIdx.x;
  int bid = blockIdx.x;
  int nwg = gridDim.x;
  if ((nwg & 7) == 0) {                           // bijective XCD swizzle (8 | nwg)
    int q = nwg >> 3;
    bid = (bid & 7) * q + (bid >> 3);
  }
  int tpb = mtiles * ntiles;
  int b  = bid / tpb;
  int t  = bid - b * tpb;
  int mt = t / ntiles;
  int nt = t - mt * ntiles;

  const u16* srcs[NST];
  int strides[NST];
  srcs[0] = Ah + (long)b * batchA + (long)mt * BM * lda;  strides[0] = lda;
  if (MODE == 0) {
    srcs[1] = Bh + (long)b * batchB + (long)nt * BN * ldb;  strides[1] = ldb;
  } else if (MODE == 1) {
    srcs[1] = Al + (long)b * batchA + (long)mt * BM * lda;  strides[1] = lda;
    srcs[2] = Bh + (long)b * batchB + (long)nt * BN * ldb;  strides[2] = ldb;
  } else {
    srcs[1] = Al + (long)b * batchA + (long)mt * BM * lda;  strides[1] = lda;
    srcs[2] = Bh + (long)b * batchB + (long)nt * BN * ldb;  strides[2] = ldb;
    srcs[3] = Bl + (long)b * batchB + (long)nt * BN * ldb;  strides[3] = ldb;
  }

  int lane = tid & 63;
  int wv   = tid >> 6;
  int wm   = (wv >> 1) << 6;       // wave 2x2 grid, 64x64 per wave
  int wn   = (wv & 1) << 6;
  int frow = lane & 15;            // mfma A/B row within 16
  int fk   = (lane >> 4) << 3;     // k-subgroup base (8 contiguous bf16)

  f32x4 acc[4][4];
#pragma unroll
  for (int i = 0; i < 4; ++i)
#pragma unroll
    for (int j = 0; j < 4; ++j) {
      f32x4 z = {0.f, 0.f, 0.f, 0.f};
      acc[i][j] = z;
    }

  int kt = K >> 6;
  for (int kk = 0; kk < kt; ++kk) {
    int k0 = kk << 6;
    // stage NST tiles: 1024 16B-chunks per tile, 4 per thread
#pragma unroll
    for (int j = 0; j < 4; ++j) {
      int c = j * 256 + tid;
      int row = c >> 3;
      int scol = (((c & 7) ^ (row & 7)) << 3);   // inverse-swizzled source column
      int lo = c << 3;
#pragma unroll
      for (int s = 0; s < NST; ++s)
        gl16(srcs[s] + (long)row * strides[s] + k0 + scol, &lds[s][lo]);
    }
    __syncthreads();   // compiler drains vmcnt before s_barrier

#pragma unroll
    for (int ks = 0; ks < 2; ++ks) {
      int kb = (ks << 5) + fk;
      bf16x8 a_h[4], a_l[4], b_h[4], b_l[4];
#pragma unroll
      for (int i = 0; i < 4; ++i) {
        int ar = wm + (i << 4) + frow;
        int ao = ar * BK + (kb ^ ((ar & 7) << 3));   // swizzled read
        a_h[i] = *(const bf16x8*)&lds[0][ao];
        if (MODE >= 1) a_l[i] = *(const bf16x8*)&lds[1][ao];
        int br = wn + (i << 4) + frow;
        int bo = br * BK + (kb ^ ((br & 7) << 3));
        b_h[i] = *(const bf16x8*)&lds[IB][bo];
        if (MODE >= 2) b_l[i] = *(const bf16x8*)&lds[3][bo];
      }
#pragma unroll
      for (int i = 0; i < 4; ++i)
#pragma unroll
        for (int j = 0; j < 4; ++j) {
          acc[i][j] = __builtin_amdgcn_mfma_f32_16x16x32_bf16(a_h[i], b_h[j], acc[i][j], 0, 0, 0);
          if (MODE >= 1)
            acc[i][j] = __builtin_amdgcn_mfma_f32_16x16x32_bf16(a_l[i], b_h[j], acc[i][j], 0, 0, 0);
          if (MODE >= 2)
            acc[i][j] = __builtin_amdgcn_mfma_f32_16x16x32_bf16(a_h[i], b_l[j], acc[i][j], 0, 0, 0);
        }
    }
    __syncthreads();
  }

  // C/D layout (m89-verified): col = lane&15, row = (lane>>4)*4 + reg
  int rbase = mt * BM + wm + ((lane >> 4) << 2);
  int cbase = nt * BN + wn + (lane & 15);
  if (MODE <= 1) {
    float* C = Cf + (long)b * batchC;
#pragma unroll
    for (int i = 0; i < 4; ++i)
#pragma unroll
      for (int j = 0; j < 4; ++j)
#pragma unroll
        for (int r = 0; r < 4; ++r)
          C[(long)(rbase + (i << 4) + r) * ldc + cbase + (j << 4)] = acc[i][j][r] * scale;
  } else {
#pragma unroll
    for (int i = 0; i < 4; ++i)
#pragma unroll
      for (int j = 0; j < 4; ++j)
#pragma unroll
        for (int r = 0; r < 4; ++r) {
          int col = cbase + (j << 4);
          float v = acc[i][j][r] + bias[col];
          long o = (long)(rbase + (i << 4) + r) * ldc + col;
          u16 h = f2bf(v);
          Ch[o] = h;
          if (MODE == 2) Cl[o] = f2bf(v - bf2f(h));
        }
  }
}

// ---- softmax over rows of 512, one wave per row; writes bf16 hi only ----
__global__ __launch_bounds__(256)
void softmax_rows(const float* __restrict__ S, u16* __restrict__ Ah) {
  int row  = (blockIdx.x << 2) + (threadIdx.x >> 6);
  int lane = threadIdx.x & 63;
  long base = (long)row * 512;
  const float4* s4 = (const float4*)(S + base);
  float v[8];
  *(float4*)&v[0] = s4[lane * 2];
  *(float4*)&v[4] = s4[lane * 2 + 1];
  float m = v[0];
#pragma unroll
  for (int j = 1; j < 8; ++j) m = fmaxf(m, v[j]);
#pragma unroll
  for (int o = 32; o > 0; o >>= 1) m = fmaxf(m, __shfl_xor(m, o));
  float sum = 0.f;
#pragma unroll
  for (int j = 0; j < 8; ++j) { v[j] = __expf(v[j] - m); sum += v[j]; }
#pragma unroll
  for (int o = 32; o > 0; o >>= 1) sum += __shfl_xor(sum, o);
  float inv = 1.f / sum;
  bf16x8 o8;
#pragma unroll
  for (int j = 0; j < 8; ++j) o8[j] = (short)f2bf(v[j] * inv);
  *(bf16x8*)&Ah[base + lane * 8] = o8;
}

extern "C" void kernel_launch(void* const* d_in, const int* in_sizes, int n_in,
                              void* d_out, int out_size, void* d_ws, size_t ws_size,
                              hipStream_t stream) {
  const float* x  = (const float*)d_in[0];
  const float* Wq = (const float*)d_in[1];
  const float* bq = (const float*)d_in[2];
  const float* Wk = (const float*)d_in[3];
  const float* bk = (const float*)d_in[4];
  const float* Wv = (const float*)d_in[5];
  const float* bv = (const float*)d_in[6];
  float* out = (float*)d_out;

  char* ws = (char*)d_ws;
  size_t off = 0;
  auto alloc = [&](size_t bytes) -> char* {
    char* p = ws + off;
    off = (off + bytes + 255) & ~(size_t)255;
    return p;
  };
  u16* WTh = (u16*)alloc((size_t)3 * 512 * 128 * 2);
  u16* WTl = (u16*)alloc((size_t)3 * 512 * 128 * 2);
  u16* xh  = (u16*)alloc((size_t)16384 * 128 * 2);
  u16* xl  = (u16*)alloc((size_t)16384 * 128 * 2);
  u16* Qh  = (u16*)alloc((size_t)16384 * 512 * 2);
  u16* Ql  = (u16*)alloc((size_t)16384 * 512 * 2);
  u16* Kh  = (u16*)alloc((size_t)16384 * 512 * 2);
  u16* Vh  = (u16*)alloc((size_t)16384 * 512 * 2);
  float* sc = (float*)alloc((size_t)32 * 512 * 512 * 4);
  u16* ah = Qh;   // attn reuses Qh (dead after scores GEMM)

  prep_w<<<768, 256, 0, stream>>>(Wq, Wk, Wv, WTh, WTl);
  split_x<<<8192, 256, 0, stream>>>(x, xh, xl, 16384 * 128);

  // projections: M=16384, N=512, K=128 -> 128x4 tiles = 512 blocks each
  nt_gemm<2><<<512, 256, 0, stream>>>(xh, xl, WTh,          WTl,          nullptr, Qh, Ql, bq,
                                      128, 128, 128, 512, 128, 4, 0, 0, 0, 1.f);
  nt_gemm<3><<<512, 256, 0, stream>>>(xh, xl, WTh + 65536,  WTl + 65536,  nullptr, Kh, nullptr, bk,
                                      128, 128, 128, 512, 128, 4, 0, 0, 0, 1.f);
  nt_gemm<3><<<512, 256, 0, stream>>>(xh, xl, WTh + 131072, WTl + 131072, nullptr, Vh, nullptr, bv,
                                      128, 128, 128, 512, 128, 4, 0, 0, 0, 1.f);

  // scores[b] = (Qh+Ql) Kh^T / 8 : batch=32, 4x4 tiles -> 512 blocks
  nt_gemm<1><<<512, 256, 0, stream>>>(Qh, Ql, Kh, nullptr, sc, nullptr, nullptr, nullptr,
                                      512, 512, 512, 512, 4, 4,
                                      262144, 262144, 262144, 0.125f);

  softmax_rows<<<4096, 256, 0, stream>>>(sc, ah);

  // out[b] = Vh attn^T : fp32 to d_out
  nt_gemm<0><<<512, 256, 0, stream>>>(Vh, nullptr, ah, nullptr, out, nullptr, nullptr, nullptr,
                                      512, 512, 512, 512, 4, 4,
                                      262144, 262144, 262144, 1.f);
}

// Round 3
// 92.918 us; speedup vs baseline: 1.6346x; 1.1338x over previous
//
#include <hip/hip_runtime.h>

// MultiHeadAttention_3753801417043 — MI355X/gfx950
// B=32, S=512, D_IN=128, N_HEAD=8, DIM_MODEL=512, SCALE=8.
//   W_eff[k][n] = sum_h W[h*128+k][n]  (concat([x]*8)@W == x@W_eff)
//   Q/K/V = x @ W_eff + b     3-pass split-bf16 MFMA, bf16-hi output
//   scores[b] = Qh·Kh^T / 8   1-pass bf16 MFMA, fp32 out
//   attn = softmax rows       bf16 hi
//   out[b] = Vh·attn^T        1-pass, fp32 out

typedef unsigned short u16;
typedef __attribute__((ext_vector_type(8))) short bf16x8;
typedef __attribute__((ext_vector_type(4))) float f32x4;
typedef __attribute__((ext_vector_type(2))) float f32x2;

__device__ inline u16 f2bf(float f) {            // round-to-nearest-even fp32->bf16
  unsigned u = __float_as_uint(f);
  u = u + 0x7fffu + ((u >> 16) & 1u);
  return (u16)(u >> 16);
}
__device__ inline float bf2f(u16 h) { return __uint_as_float(((unsigned)h) << 16); }

// async global->LDS, 16B per lane (wave-uniform LDS base + lane*16; linear layout)
__device__ inline void gl16(const u16* g, u16* l) {
  __builtin_amdgcn_global_load_lds(
      (const __attribute__((address_space(1))) unsigned int*)g,
      (__attribute__((address_space(3))) unsigned int*)l, 16, 0, 0);
}

// ---- W_eff prep, LDS-transposed: coalesced reads, 16B coalesced writes ----
// grid 96 = 3 proj × 32 n-blocks of 16; WT[t][n][k], k fastest.
__global__ __launch_bounds__(256)
void prep_w(const float* __restrict__ Wq, const float* __restrict__ Wk,
            const float* __restrict__ Wv,
            u16* __restrict__ WTh, u16* __restrict__ WTl) {
  __shared__ float sm[128][17];
  int t  = blockIdx.x >> 5;
  int nb = blockIdx.x & 31;
  const float* W = (t == 0) ? Wq : (t == 1) ? Wk : Wv;
  int n0 = nb << 4;
  int nl = threadIdx.x & 15;         // n within tile (contiguous lanes -> coalesced)
  int kq = threadIdx.x >> 4;         // 0..15
  float s[8];
#pragma unroll
  for (int i = 0; i < 8; ++i) s[i] = 0.f;
#pragma unroll
  for (int h = 0; h < 8; ++h)
#pragma unroll
    for (int i = 0; i < 8; ++i)
      s[i] += W[(h * 128 + kq + (i << 4)) * 512 + n0 + nl];
#pragma unroll
  for (int i = 0; i < 8; ++i) sm[kq + (i << 4)][nl] = s[i];
  __syncthreads();
  int no = threadIdx.x >> 4;         // output row n (16 rows/block)
  int k8 = (threadIdx.x & 15) << 3;  // 8-k chunk
  bf16x8 h8, l8;
#pragma unroll
  for (int c = 0; c < 8; ++c) {
    float v = sm[k8 + c][no];
    u16 h = f2bf(v);
    h8[c] = (short)h;
    l8[c] = (short)f2bf(v - bf2f(h));
  }
  long o = (long)t * 65536 + (long)(n0 + no) * 128 + k8;
  *(bf16x8*)&WTh[o] = h8;
  *(bf16x8*)&WTl[o] = l8;
}

// ---- x split into bf16 hi/lo, vectorized 8/thread; grid 1024 ----
__global__ __launch_bounds__(256)
void split_x(const float* __restrict__ x, u16* __restrict__ xh, u16* __restrict__ xl) {
  int i = blockIdx.x * 256 + threadIdx.x;      // 262144 groups of 8
  const f32x4* xx = (const f32x4*)x;
  f32x4 a = xx[i * 2], b = xx[i * 2 + 1];
  float v[8] = {a[0], a[1], a[2], a[3], b[0], b[1], b[2], b[3]};
  bf16x8 h8, l8;
#pragma unroll
  for (int j = 0; j < 8; ++j) {
    u16 h = f2bf(v[j]);
    h8[j] = (short)h;
    l8[j] = (short)f2bf(v[j] - bf2f(h));
  }
  ((bf16x8*)xh)[i] = h8;
  ((bf16x8*)xl)[i] = l8;
}

// ---- fused Q/K/V projection: 3-pass split-bf16, coalesced bf16 epilogue ----
// grid 1536 = (128 mt × 4 nt) × 3 which, which fastest (x-tile L2 reuse).
// K=128 (2 k-iters). LDS: 64KB staging, reused as per-wave fp32 transpose pad.
__global__ __launch_bounds__(256, 2)
void proj_fused(const u16* __restrict__ xh, const u16* __restrict__ xl,
                const u16* __restrict__ WTh, const u16* __restrict__ WTl,
                u16* __restrict__ Qh, u16* __restrict__ Kh, u16* __restrict__ Vh,
                const float* __restrict__ bq, const float* __restrict__ bk,
                const float* __restrict__ bv) {
  __shared__ __align__(16) char ldsraw[65536];
  u16* st = (u16*)ldsraw;            // 4 tiles × 8192 u16

  int tid = threadIdx.x;
  int bid = blockIdx.x;
  bid = (bid & 7) * 192 + (bid >> 3);          // XCD swizzle (1536 = 8×192)
  int which = bid % 3;
  int tile  = bid / 3;
  int mt = tile >> 2;
  int nt = tile & 3;

  const u16* Ah = xh + (long)mt * (128 * 128);
  const u16* Al = xl + (long)mt * (128 * 128);
  const u16* Bh = WTh + which * 65536 + nt * 16384;
  const u16* Bl = WTl + which * 65536 + nt * 16384;
  const float* bias = (which == 0) ? bq : (which == 1) ? bk : bv;
  u16* C = (which == 0) ? Qh : (which == 1) ? Kh : Vh;

  int lane = tid & 63;
  int wv = tid >> 6;
  int wm = (wv >> 1) << 6;
  int wn = (wv & 1) << 6;
  int frow = lane & 15;
  int fk = (lane >> 4) << 3;

  f32x4 acc[4][4];
#pragma unroll
  for (int i = 0; i < 4; ++i)
#pragma unroll
    for (int j = 0; j < 4; ++j) {
      f32x4 z = {0.f, 0.f, 0.f, 0.f};
      acc[i][j] = z;
    }

  for (int kk = 0; kk < 2; ++kk) {
    int k0 = kk << 6;
#pragma unroll
    for (int j = 0; j < 4; ++j) {
      int c = j * 256 + tid;
      int row = c >> 3;
      int scol = ((c & 7) ^ (row & 7)) << 3;   // inverse-swizzled source column
      int ga = row * 128 + k0 + scol;          // lda == ldb == 128
      int lo = c << 3;
      gl16(Ah + ga, st + lo);
      gl16(Al + ga, st + 8192 + lo);
      gl16(Bh + ga, st + 16384 + lo);
      gl16(Bl + ga, st + 24576 + lo);
    }
    __syncthreads();
#pragma unroll
    for (int ks = 0; ks < 2; ++ks) {
      int kb = (ks << 5) + fk;
      bf16x8 a_h[4], a_l[4], b_h[4], b_l[4];
#pragma unroll
      for (int i = 0; i < 4; ++i) {
        int ar = wm + (i << 4) + frow;
        int ao = ar * 64 + (kb ^ ((ar & 7) << 3));   // swizzled read
        a_h[i] = *(const bf16x8*)&st[ao];
        a_l[i] = *(const bf16x8*)&st[8192 + ao];
        int br = wn + (i << 4) + frow;
        int bo = br * 64 + (kb ^ ((br & 7) << 3));
        b_h[i] = *(const bf16x8*)&st[16384 + bo];
        b_l[i] = *(const bf16x8*)&st[24576 + bo];
      }
#pragma unroll
      for (int i = 0; i < 4; ++i)
#pragma unroll
        for (int j = 0; j < 4; ++j) {
          acc[i][j] = __builtin_amdgcn_mfma_f32_16x16x32_bf16(a_h[i], b_h[j], acc[i][j], 0, 0, 0);
          acc[i][j] = __builtin_amdgcn_mfma_f32_16x16x32_bf16(a_l[i], b_h[j], acc[i][j], 0, 0, 0);
          acc[i][j] = __builtin_amdgcn_mfma_f32_16x16x32_bf16(a_h[i], b_l[j], acc[i][j], 0, 0, 0);
        }
    }
    __syncthreads();
  }

  // Coalesced epilogue: per-wave fp32 transpose in LDS (stride 66 -> 2-way = free),
  // two 32-row half passes (per-wave region 32×66×4B, total 33.8KB < staging 64KB).
  // Intra-wave only: LDS pipe is in-order per wave, no barrier needed.
  float* tr = ((float*)ldsraw) + wv * 2112;    // 32*66
  int lr = lane >> 3;
  int c8 = (lane & 7) << 3;
  int colbase = (nt << 7) + wn + c8;
  float bb[8];
#pragma unroll
  for (int c = 0; c < 8; ++c) bb[c] = bias[colbase + c];
  long rowg0 = (long)(mt << 7) + wm;
#pragma unroll
  for (int q = 0; q < 2; ++q) {
#pragma unroll
    for (int il = 0; il < 2; ++il) {
      int i = (q << 1) + il;
#pragma unroll
      for (int j = 0; j < 4; ++j)
#pragma unroll
        for (int r = 0; r < 4; ++r)
          tr[((il << 4) + ((lane >> 4) << 2) + r) * 66 + (j << 4) + (lane & 15)] =
              acc[i][j][r];
    }
#pragma unroll
    for (int p = 0; p < 4; ++p) {
      int rr = (p << 3) + lr;
      float v[8];
      *(f32x2*)&v[0] = *(const f32x2*)&tr[rr * 66 + c8];
      *(f32x2*)&v[2] = *(const f32x2*)&tr[rr * 66 + c8 + 2];
      *(f32x2*)&v[4] = *(const f32x2*)&tr[rr * 66 + c8 + 4];
      *(f32x2*)&v[6] = *(const f32x2*)&tr[rr * 66 + c8 + 6];
      bf16x8 o8;
#pragma unroll
      for (int c = 0; c < 8; ++c) o8[c] = (short)f2bf(v[c] + bb[c]);
      *(bf16x8*)&C[(rowg0 + (q << 5) + rr) * 512 + colbase] = o8;
    }
  }
}

// ---- batched 512³ NT GEMM, 1-pass bf16, fp32 out ----
// grid 512 = 32 batches × 16 tiles; LDS 32KB -> 4 blocks/CU.
__global__ __launch_bounds__(256, 4)
void nt_gemm1(const u16* __restrict__ A, const u16* __restrict__ B,
              float* __restrict__ C, float scale) {
  __shared__ __align__(16) u16 lds[2][128 * 64];
  int tid = threadIdx.x;
  int bid = blockIdx.x;
  bid = (bid & 7) * 64 + (bid >> 3);           // XCD swizzle: 4 batches/XCD
  int b  = bid >> 4;
  int t  = bid & 15;
  int mt = t >> 2;
  int nt = t & 3;
  const u16* pA = A + (long)b * 262144 + (long)mt * (128 * 512);
  const u16* pB = B + (long)b * 262144 + (long)nt * (128 * 512);

  int lane = tid & 63;
  int wv = tid >> 6;
  int wm = (wv >> 1) << 6;
  int wn = (wv & 1) << 6;
  int frow = lane & 15;
  int fk = (lane >> 4) << 3;

  f32x4 acc[4][4];
#pragma unroll
  for (int i = 0; i < 4; ++i)
#pragma unroll
    for (int j = 0; j < 4; ++j) {
      f32x4 z = {0.f, 0.f, 0.f, 0.f};
      acc[i][j] = z;
    }

  for (int kk = 0; kk < 8; ++kk) {
    int k0 = kk << 6;
#pragma unroll
    for (int j = 0; j < 4; ++j) {
      int c = j * 256 + tid;
      int row = c >> 3;
      int scol = ((c & 7) ^ (row & 7)) << 3;
      long g = (long)row * 512 + k0 + scol;
      int lo = c << 3;
      gl16(pA + g, &lds[0][lo]);
      gl16(pB + g, &lds[1][lo]);
    }
    __syncthreads();
#pragma unroll
    for (int ks = 0; ks < 2; ++ks) {
      int kb = (ks << 5) + fk;
      bf16x8 av[4], bv_[4];
#pragma unroll
      for (int i = 0; i < 4; ++i) {
        int ar = wm + (i << 4) + frow;
        av[i] = *(const bf16x8*)&lds[0][ar * 64 + (kb ^ ((ar & 7) << 3))];
        int br = wn + (i << 4) + frow;
        bv_[i] = *(const bf16x8*)&lds[1][br * 64 + (kb ^ ((br & 7) << 3))];
      }
#pragma unroll
      for (int i = 0; i < 4; ++i)
#pragma unroll
        for (int j = 0; j < 4; ++j)
          acc[i][j] = __builtin_amdgcn_mfma_f32_16x16x32_bf16(av[i], bv_[j], acc[i][j], 0, 0, 0);
    }
    __syncthreads();
  }

  int rbase = (mt << 7) + wm + ((lane >> 4) << 2);
  int cbase = (nt << 7) + wn + (lane & 15);
  float* Cb = C + (long)b * 262144;
#pragma unroll
  for (int i = 0; i < 4; ++i)
#pragma unroll
    for (int j = 0; j < 4; ++j)
#pragma unroll
      for (int r = 0; r < 4; ++r)
        Cb[(long)(rbase + (i << 4) + r) * 512 + cbase + (j << 4)] = acc[i][j][r] * scale;
}

// ---- softmax over rows of 512, one wave per row; writes bf16 hi ----
__global__ __launch_bounds__(256)
void softmax_rows(const float* __restrict__ S, u16* __restrict__ Ah) {
  int row  = (blockIdx.x << 2) + (threadIdx.x >> 6);
  int lane = threadIdx.x & 63;
  long base = (long)row * 512;
  const f32x4* s4 = (const f32x4*)(S + base);
  float v[8];
  *(f32x4*)&v[0] = s4[lane * 2];
  *(f32x4*)&v[4] = s4[lane * 2 + 1];
  float m = v[0];
#pragma unroll
  for (int j = 1; j < 8; ++j) m = fmaxf(m, v[j]);
#pragma unroll
  for (int o = 32; o > 0; o >>= 1) m = fmaxf(m, __shfl_xor(m, o));
  float sum = 0.f;
#pragma unroll
  for (int j = 0; j < 8; ++j) { v[j] = __expf(v[j] - m); sum += v[j]; }
#pragma unroll
  for (int o = 32; o > 0; o >>= 1) sum += __shfl_xor(sum, o);
  float inv = 1.f / sum;
  bf16x8 o8;
#pragma unroll
  for (int j = 0; j < 8; ++j) o8[j] = (short)f2bf(v[j] * inv);
  *(bf16x8*)&Ah[base + lane * 8] = o8;
}

extern "C" void kernel_launch(void* const* d_in, const int* in_sizes, int n_in,
                              void* d_out, int out_size, void* d_ws, size_t ws_size,
                              hipStream_t stream) {
  const float* x  = (const float*)d_in[0];
  const float* Wq = (const float*)d_in[1];
  const float* bq = (const float*)d_in[2];
  const float* Wk = (const float*)d_in[3];
  const float* bk = (const float*)d_in[4];
  const float* Wv = (const float*)d_in[5];
  const float* bv = (const float*)d_in[6];
  float* out = (float*)d_out;

  char* ws = (char*)d_ws;
  size_t off = 0;
  auto alloc = [&](size_t bytes) -> char* {
    char* p = ws + off;
    off = (off + bytes + 255) & ~(size_t)255;
    return p;
  };
  u16* WTh = (u16*)alloc((size_t)3 * 512 * 128 * 2);
  u16* WTl = (u16*)alloc((size_t)3 * 512 * 128 * 2);
  u16* xh  = (u16*)alloc((size_t)16384 * 128 * 2);
  u16* xl  = (u16*)alloc((size_t)16384 * 128 * 2);
  u16* Qh  = (u16*)alloc((size_t)16384 * 512 * 2);
  u16* Kh  = (u16*)alloc((size_t)16384 * 512 * 2);
  u16* Vh  = (u16*)alloc((size_t)16384 * 512 * 2);
  float* sc = (float*)alloc((size_t)32 * 512 * 512 * 4);
  u16* ah = Qh;   // attn reuses Qh (dead after scores GEMM)

  prep_w<<<96, 256, 0, stream>>>(Wq, Wk, Wv, WTh, WTl);
  split_x<<<1024, 256, 0, stream>>>(x, xh, xl);
  proj_fused<<<1536, 256, 0, stream>>>(xh, xl, WTh, WTl, Qh, Kh, Vh, bq, bk, bv);
  nt_gemm1<<<512, 256, 0, stream>>>(Qh, Kh, sc, 0.125f);
  softmax_rows<<<4096, 256, 0, stream>>>(sc, ah);
  nt_gemm1<<<512, 256, 0, stream>>>(Vh, ah, out, 1.f);
}

// Round 4
// 87.239 us; speedup vs baseline: 1.7410x; 1.0651x over previous
//
#include <hip/hip_runtime.h>

// MultiHeadAttention_3753801417043 — MI355X/gfx950
// B=32, S=512, D_IN=128, N_HEAD=8, DIM_MODEL=512, SCALE=8.
//   W_eff[k][n] = sum_h W[h*128+k][n]  (concat([x]*8)@W == x@W_eff)
//   Q/K/V = x @ W_eff + b     3-pass split-bf16 MFMA, bf16-hi output
//   fused attention:          S = Qh·Kh^T (fp32 regs) -> softmax -> P bf16 in LDS
//                             OUT = Vh·P^T            (one kernel, no sc/attn in HBM)

typedef unsigned short u16;
typedef __attribute__((ext_vector_type(8))) short bf16x8;
typedef __attribute__((ext_vector_type(4))) float f32x4;
typedef __attribute__((ext_vector_type(2))) float f32x2;

__device__ inline u16 f2bf(float f) {            // round-to-nearest-even fp32->bf16
  unsigned u = __float_as_uint(f);
  u = u + 0x7fffu + ((u >> 16) & 1u);
  return (u16)(u >> 16);
}
__device__ inline float bf2f(u16 h) { return __uint_as_float(((unsigned)h) << 16); }

// async global->LDS, 16B per lane (wave-uniform LDS base + lane*16; linear layout)
__device__ inline void gl16(const u16* g, u16* l) {
  __builtin_amdgcn_global_load_lds(
      (const __attribute__((address_space(1))) unsigned int*)g,
      (__attribute__((address_space(3))) unsigned int*)l, 16, 0, 0);
}

// ---- W_eff prep, LDS-transposed: coalesced reads, 16B coalesced writes ----
__global__ __launch_bounds__(256)
void prep_w(const float* __restrict__ Wq, const float* __restrict__ Wk,
            const float* __restrict__ Wv,
            u16* __restrict__ WTh, u16* __restrict__ WTl) {
  __shared__ float sm[128][17];
  int t  = blockIdx.x >> 5;
  int nb = blockIdx.x & 31;
  const float* W = (t == 0) ? Wq : (t == 1) ? Wk : Wv;
  int n0 = nb << 4;
  int nl = threadIdx.x & 15;
  int kq = threadIdx.x >> 4;
  float s[8];
#pragma unroll
  for (int i = 0; i < 8; ++i) s[i] = 0.f;
#pragma unroll
  for (int h = 0; h < 8; ++h)
#pragma unroll
    for (int i = 0; i < 8; ++i)
      s[i] += W[(h * 128 + kq + (i << 4)) * 512 + n0 + nl];
#pragma unroll
  for (int i = 0; i < 8; ++i) sm[kq + (i << 4)][nl] = s[i];
  __syncthreads();
  int no = threadIdx.x >> 4;
  int k8 = (threadIdx.x & 15) << 3;
  bf16x8 h8, l8;
#pragma unroll
  for (int c = 0; c < 8; ++c) {
    float v = sm[k8 + c][no];
    u16 h = f2bf(v);
    h8[c] = (short)h;
    l8[c] = (short)f2bf(v - bf2f(h));
  }
  long o = (long)t * 65536 + (long)(n0 + no) * 128 + k8;
  *(bf16x8*)&WTh[o] = h8;
  *(bf16x8*)&WTl[o] = l8;
}

// ---- x split into bf16 hi/lo ----
__global__ __launch_bounds__(256)
void split_x(const float* __restrict__ x, u16* __restrict__ xh, u16* __restrict__ xl) {
  int i = blockIdx.x * 256 + threadIdx.x;
  const f32x4* xx = (const f32x4*)x;
  f32x4 a = xx[i * 2], b = xx[i * 2 + 1];
  float v[8] = {a[0], a[1], a[2], a[3], b[0], b[1], b[2], b[3]};
  bf16x8 h8, l8;
#pragma unroll
  for (int j = 0; j < 8; ++j) {
    u16 h = f2bf(v[j]);
    h8[j] = (short)h;
    l8[j] = (short)f2bf(v[j] - bf2f(h));
  }
  ((bf16x8*)xh)[i] = h8;
  ((bf16x8*)xl)[i] = l8;
}

// ---- fused Q/K/V projection: 3-pass split-bf16, coalesced bf16 epilogue ----
__global__ __launch_bounds__(256, 2)
void proj_fused(const u16* __restrict__ xh, const u16* __restrict__ xl,
                const u16* __restrict__ WTh, const u16* __restrict__ WTl,
                u16* __restrict__ Qh, u16* __restrict__ Kh, u16* __restrict__ Vh,
                const float* __restrict__ bq, const float* __restrict__ bk,
                const float* __restrict__ bv) {
  __shared__ __align__(16) char ldsraw[65536];
  u16* st = (u16*)ldsraw;

  int tid = threadIdx.x;
  int bid = blockIdx.x;
  bid = (bid & 7) * 192 + (bid >> 3);          // XCD swizzle (1536 = 8×192)
  int which = bid % 3;
  int tile  = bid / 3;
  int mt = tile >> 2;
  int nt = tile & 3;

  const u16* Ah = xh + (long)mt * (128 * 128);
  const u16* Al = xl + (long)mt * (128 * 128);
  const u16* Bh = WTh + which * 65536 + nt * 16384;
  const u16* Bl = WTl + which * 65536 + nt * 16384;
  const float* bias = (which == 0) ? bq : (which == 1) ? bk : bv;
  u16* C = (which == 0) ? Qh : (which == 1) ? Kh : Vh;

  int lane = tid & 63;
  int wv = tid >> 6;
  int wm = (wv >> 1) << 6;
  int wn = (wv & 1) << 6;
  int frow = lane & 15;
  int fk = (lane >> 4) << 3;

  f32x4 acc[4][4];
#pragma unroll
  for (int i = 0; i < 4; ++i)
#pragma unroll
    for (int j = 0; j < 4; ++j) {
      f32x4 z = {0.f, 0.f, 0.f, 0.f};
      acc[i][j] = z;
    }

  for (int kk = 0; kk < 2; ++kk) {
    int k0 = kk << 6;
#pragma unroll
    for (int j = 0; j < 4; ++j) {
      int c = j * 256 + tid;
      int row = c >> 3;
      int scol = ((c & 7) ^ (row & 7)) << 3;
      int ga = row * 128 + k0 + scol;
      int lo = c << 3;
      gl16(Ah + ga, st + lo);
      gl16(Al + ga, st + 8192 + lo);
      gl16(Bh + ga, st + 16384 + lo);
      gl16(Bl + ga, st + 24576 + lo);
    }
    __syncthreads();
#pragma unroll
    for (int ks = 0; ks < 2; ++ks) {
      int kb = (ks << 5) + fk;
      bf16x8 a_h[4], a_l[4], b_h[4], b_l[4];
#pragma unroll
      for (int i = 0; i < 4; ++i) {
        int ar = wm + (i << 4) + frow;
        int ao = ar * 64 + (kb ^ ((ar & 7) << 3));
        a_h[i] = *(const bf16x8*)&st[ao];
        a_l[i] = *(const bf16x8*)&st[8192 + ao];
        int br = wn + (i << 4) + frow;
        int bo = br * 64 + (kb ^ ((br & 7) << 3));
        b_h[i] = *(const bf16x8*)&st[16384 + bo];
        b_l[i] = *(const bf16x8*)&st[24576 + bo];
      }
#pragma unroll
      for (int i = 0; i < 4; ++i)
#pragma unroll
        for (int j = 0; j < 4; ++j) {
          acc[i][j] = __builtin_amdgcn_mfma_f32_16x16x32_bf16(a_h[i], b_h[j], acc[i][j], 0, 0, 0);
          acc[i][j] = __builtin_amdgcn_mfma_f32_16x16x32_bf16(a_l[i], b_h[j], acc[i][j], 0, 0, 0);
          acc[i][j] = __builtin_amdgcn_mfma_f32_16x16x32_bf16(a_h[i], b_l[j], acc[i][j], 0, 0, 0);
        }
    }
    __syncthreads();
  }

  // Coalesced epilogue via per-wave fp32 LDS transpose (intra-wave, no barrier)
  float* tr = ((float*)ldsraw) + wv * 2112;
  int lr = lane >> 3;
  int c8 = (lane & 7) << 3;
  int colbase = (nt << 7) + wn + c8;
  float bb[8];
#pragma unroll
  for (int c = 0; c < 8; ++c) bb[c] = bias[colbase + c];
  long rowg0 = (long)(mt << 7) + wm;
#pragma unroll
  for (int q = 0; q < 2; ++q) {
#pragma unroll
    for (int il = 0; il < 2; ++il) {
      int i = (q << 1) + il;
#pragma unroll
      for (int j = 0; j < 4; ++j)
#pragma unroll
        for (int r = 0; r < 4; ++r)
          tr[((il << 4) + ((lane >> 4) << 2) + r) * 66 + (j << 4) + (lane & 15)] =
              acc[i][j][r];
    }
#pragma unroll
    for (int p = 0; p < 4; ++p) {
      int rr = (p << 3) + lr;
      float v[8];
      *(f32x2*)&v[0] = *(const f32x2*)&tr[rr * 66 + c8];
      *(f32x2*)&v[2] = *(const f32x2*)&tr[rr * 66 + c8 + 2];
      *(f32x2*)&v[4] = *(const f32x2*)&tr[rr * 66 + c8 + 4];
      *(f32x2*)&v[6] = *(const f32x2*)&tr[rr * 66 + c8 + 6];
      bf16x8 o8;
#pragma unroll
      for (int c = 0; c < 8; ++c) o8[c] = (short)f2bf(v[c] + bb[c]);
      *(bf16x8*)&C[(rowg0 + (q << 5) + rr) * 512 + colbase] = o8;
    }
  }
}

// ---- fused attention: S = Q·K^T/8, softmax, OUT = V·P^T, one block = 64 attn rows ----
// grid 256 = 32 batches × 8 jblocks, 512 threads.
// LDS map (128 KB): phase1 Q[0,8K) K[8K,72K); scratch smax/ssum [72K,74K) (read
// strictly before phase2 staging); P bf16 [0,64K) XOR-swz (row&7)<<4; V [64K,128K).
__global__ __launch_bounds__(512, 1)
void attn_fused(const u16* __restrict__ Q, const u16* __restrict__ K,
                const u16* __restrict__ V, float* __restrict__ OUT) {
  __shared__ __align__(16) char LDS[131072];
  u16* ldsQ = (u16*)LDS;
  u16* ldsK = (u16*)(LDS + 8192);
  u16* ldsV = (u16*)(LDS + 65536);
  float* smax = (float*)(LDS + 73728);
  float* ssum = (float*)(LDS + 74752);

  int tid = threadIdx.x;
  int bid = blockIdx.x;
  bid = (bid & 7) * 32 + (bid >> 3);     // XCD swizzle: 4 batches per XCD
  int b  = bid >> 3;
  int jb = bid & 7;

  const u16* Qp = Q + ((long)b * 512 + jb * 64) * 512;
  const u16* Kp = K + (long)b * 262144;
  const u16* Vp = V + (long)b * 262144;

  int lane = tid & 63;
  int wv   = tid >> 6;
  int frow = lane & 15;
  int hi4  = lane >> 4;
  int fk   = hi4 << 3;

  // ---------------- phase 1: S = Q K^T (M=64, N=512, contraction 512) ----------------
  int wm1 = (wv >> 2) << 5;      // 0,32
  int wn1 = (wv & 3) << 7;       // 0,128,256,384
  f32x4 acc[2][8];
#pragma unroll
  for (int i = 0; i < 2; ++i)
#pragma unroll
    for (int j = 0; j < 8; ++j) {
      f32x4 z = {0.f, 0.f, 0.f, 0.f};
      acc[i][j] = z;
    }

  int qrow = tid >> 3, qcc = tid & 7;
  int qscol = (qcc ^ (qrow & 7)) << 3;
  for (int kk = 0; kk < 8; ++kk) {
    int k0 = kk << 6;
    gl16(Qp + qrow * 512 + k0 + qscol, ldsQ + tid * 8);
#pragma unroll
    for (int j = 0; j < 8; ++j) {
      int c = (j << 9) + tid;
      int row = c >> 3, cc = c & 7;
      int scol = (cc ^ (row & 7)) << 3;
      gl16(Kp + (long)row * 512 + k0 + scol, ldsK + c * 8);
    }
    __syncthreads();
#pragma unroll
    for (int ks = 0; ks < 2; ++ks) {
      int kb = (ks << 5) + fk;
      bf16x8 a[2], bb[8];
#pragma unroll
      for (int i = 0; i < 2; ++i) {
        int ar = wm1 + (i << 4) + frow;
        a[i] = *(const bf16x8*)&ldsQ[ar * 64 + (kb ^ ((ar & 7) << 3))];
      }
#pragma unroll
      for (int j = 0; j < 8; ++j) {
        int br = wn1 + (j << 4) + frow;
        bb[j] = *(const bf16x8*)&ldsK[br * 64 + (kb ^ ((br & 7) << 3))];
      }
#pragma unroll
      for (int i = 0; i < 2; ++i)
#pragma unroll
        for (int j = 0; j < 8; ++j)
          acc[i][j] = __builtin_amdgcn_mfma_f32_16x16x32_bf16(a[i], bb[j], acc[i][j], 0, 0, 0);
    }
    __syncthreads();
  }

  // ---------------- softmax over N=512 (rows span 4 column-waves) ----------------
  float mx[2][4];
#pragma unroll
  for (int i = 0; i < 2; ++i)
#pragma unroll
    for (int r = 0; r < 4; ++r) {
      float m = acc[i][0][r];
#pragma unroll
      for (int j = 1; j < 8; ++j) m = fmaxf(m, acc[i][j][r]);
      mx[i][r] = m;
    }
#pragma unroll
  for (int msk = 1; msk < 16; msk <<= 1)
#pragma unroll
    for (int i = 0; i < 2; ++i)
#pragma unroll
      for (int r = 0; r < 4; ++r)
        mx[i][r] = fmaxf(mx[i][r], __shfl_xor(mx[i][r], msk));
  if (frow == 0) {
#pragma unroll
    for (int i = 0; i < 2; ++i)
#pragma unroll
      for (int r = 0; r < 4; ++r)
        smax[(wm1 + (i << 4) + (hi4 << 2) + r) * 4 + (wv & 3)] = mx[i][r];
  }
  __syncthreads();
  float mf[2][4];
#pragma unroll
  for (int i = 0; i < 2; ++i)
#pragma unroll
    for (int r = 0; r < 4; ++r) {
      f32x4 mv = *(const f32x4*)&smax[(wm1 + (i << 4) + (hi4 << 2) + r) * 4];
      mf[i][r] = fmaxf(fmaxf(mv[0], mv[1]), fmaxf(mv[2], mv[3]));
    }
  float sm[2][4];
#pragma unroll
  for (int i = 0; i < 2; ++i)
#pragma unroll
    for (int r = 0; r < 4; ++r) sm[i][r] = 0.f;
#pragma unroll
  for (int i = 0; i < 2; ++i)
#pragma unroll
    for (int j = 0; j < 8; ++j)
#pragma unroll
      for (int r = 0; r < 4; ++r) {
        float p = __expf((acc[i][j][r] - mf[i][r]) * 0.125f);   // fold /8 scale
        acc[i][j][r] = p;
        sm[i][r] += p;
      }
#pragma unroll
  for (int msk = 1; msk < 16; msk <<= 1)
#pragma unroll
    for (int i = 0; i < 2; ++i)
#pragma unroll
      for (int r = 0; r < 4; ++r)
        sm[i][r] += __shfl_xor(sm[i][r], msk);
  if (frow == 0) {
#pragma unroll
    for (int i = 0; i < 2; ++i)
#pragma unroll
      for (int r = 0; r < 4; ++r)
        ssum[(wm1 + (i << 4) + (hi4 << 2) + r) * 4 + (wv & 3)] = sm[i][r];
  }
  __syncthreads();
  float inv[2][4];
#pragma unroll
  for (int i = 0; i < 2; ++i)
#pragma unroll
    for (int r = 0; r < 4; ++r) {
      f32x4 sv = *(const f32x4*)&ssum[(wm1 + (i << 4) + (hi4 << 2) + r) * 4];
      inv[i][r] = 1.f / (sv[0] + sv[1] + sv[2] + sv[3]);
    }
  // write P (bf16) to LDS [64 rows][512 cols], byte-XOR swizzle by (row&7)<<4
#pragma unroll
  for (int i = 0; i < 2; ++i)
#pragma unroll
    for (int j = 0; j < 8; ++j)
#pragma unroll
      for (int r = 0; r < 4; ++r) {
        int row = wm1 + (i << 4) + (hi4 << 2) + r;
        int col = wn1 + (j << 4) + frow;
        int byt = ((row << 10) + (col << 1)) ^ ((row & 7) << 4);
        *(u16*)(LDS + byt) = f2bf(acc[i][j][r] * inv[i][r]);
      }
  __syncthreads();   // P complete; scratch reads done before V staging overwrites it

  // ---------------- phase 2: OUT[:, jb*64+..] = V · P^T (M=512, N=64, K=512) ----------------
  int wm2 = (wv >> 1) << 7;      // 0,128,256,384
  int wn2 = (wv & 1) << 5;       // 0,32
  f32x4 a2[8][2];
#pragma unroll
  for (int i = 0; i < 8; ++i)
#pragma unroll
    for (int j = 0; j < 2; ++j) {
      f32x4 z = {0.f, 0.f, 0.f, 0.f};
      a2[i][j] = z;
    }

  for (int kk = 0; kk < 8; ++kk) {
    int k0 = kk << 6;
#pragma unroll
    for (int j = 0; j < 8; ++j) {
      int c = (j << 9) + tid;
      int row = c >> 3, cc = c & 7;
      int scol = (cc ^ (row & 7)) << 3;
      gl16(Vp + (long)row * 512 + k0 + scol, ldsV + c * 8);
    }
    __syncthreads();
#pragma unroll
    for (int ks = 0; ks < 2; ++ks) {
      int kb = (ks << 5) + fk;
      bf16x8 a[8], bb[2];
#pragma unroll
      for (int i = 0; i < 8; ++i) {
        int ar = wm2 + (i << 4) + frow;
        a[i] = *(const bf16x8*)&ldsV[ar * 64 + (kb ^ ((ar & 7) << 3))];
      }
#pragma unroll
      for (int j = 0; j < 2; ++j) {
        int br = wn2 + (j << 4) + frow;
        int byt = ((br << 10) + ((k0 + kb) << 1)) ^ ((br & 7) << 4);
        bb[j] = *(const bf16x8*)(LDS + byt);
      }
#pragma unroll
      for (int i = 0; i < 8; ++i)
#pragma unroll
        for (int j = 0; j < 2; ++j)
          a2[i][j] = __builtin_amdgcn_mfma_f32_16x16x32_bf16(a[i], bb[j], a2[i][j], 0, 0, 0);
    }
    __syncthreads();
  }

  // epilogue: OUT row = V row, col = jb*64 + local
  float* Ob = OUT + (long)b * 262144 + jb * 64;
#pragma unroll
  for (int i = 0; i < 8; ++i)
#pragma unroll
    for (int j = 0; j < 2; ++j)
#pragma unroll
      for (int r = 0; r < 4; ++r) {
        int row = wm2 + (i << 4) + (hi4 << 2) + r;
        int col = wn2 + (j << 4) + frow;
        Ob[(long)row * 512 + col] = a2[i][j][r];
      }
}

extern "C" void kernel_launch(void* const* d_in, const int* in_sizes, int n_in,
                              void* d_out, int out_size, void* d_ws, size_t ws_size,
                              hipStream_t stream) {
  const float* x  = (const float*)d_in[0];
  const float* Wq = (const float*)d_in[1];
  const float* bq = (const float*)d_in[2];
  const float* Wk = (const float*)d_in[3];
  const float* bk = (const float*)d_in[4];
  const float* Wv = (const float*)d_in[5];
  const float* bv = (const float*)d_in[6];
  float* out = (float*)d_out;

  char* ws = (char*)d_ws;
  size_t off = 0;
  auto alloc = [&](size_t bytes) -> char* {
    char* p = ws + off;
    off = (off + bytes + 255) & ~(size_t)255;
    return p;
  };
  u16* WTh = (u16*)alloc((size_t)3 * 512 * 128 * 2);
  u16* WTl = (u16*)alloc((size_t)3 * 512 * 128 * 2);
  u16* xh  = (u16*)alloc((size_t)16384 * 128 * 2);
  u16* xl  = (u16*)alloc((size_t)16384 * 128 * 2);
  u16* Qh  = (u16*)alloc((size_t)16384 * 512 * 2);
  u16* Kh  = (u16*)alloc((size_t)16384 * 512 * 2);
  u16* Vh  = (u16*)alloc((size_t)16384 * 512 * 2);

  prep_w<<<96, 256, 0, stream>>>(Wq, Wk, Wv, WTh, WTl);
  split_x<<<1024, 256, 0, stream>>>(x, xh, xl);
  proj_fused<<<1536, 256, 0, stream>>>(xh, xl, WTh, WTl, Qh, Kh, Vh, bq, bk, bv);
  attn_fused<<<256, 512, 0, stream>>>(Qh, Kh, Vh, out);
}